// Round 1
// baseline (2889.626 us; speedup 1.0000x reference)
//
#include <hip/hip_runtime.h>
#include <cstdint>
#include <cstddef>

#define Bq   4
#define Nq   8192
#define Cq   128
#define NPq  2048
#define NSq  16
#define KSEL 17

// --- numerics helpers (rn ops block fma-contraction; must match numpy fp32 order) ---
__device__ __forceinline__ float rn_sq3(float x, float y, float z) {
  return __fadd_rn(__fadd_rn(__fmul_rn(x, x), __fmul_rn(y, y)), __fmul_rn(z, z));
}

// expanded-form squared distance, matching ref: max(sumq + sump - 2*dot, 0)
__device__ __forceinline__ float sq_expand(float qx, float qy, float qz, float sq_,
                                           float px, float py, float pz, float sp_) {
  float dot = __fadd_rn(__fadd_rn(__fmul_rn(qx, px), __fmul_rn(qy, py)), __fmul_rn(qz, pz));
  float v = __fsub_rn(__fadd_rn(sq_, sp_), __fmul_rn(2.0f, dot));
  v = fmaxf(v, 0.0f);
  return __fadd_rn(v, 0.0f);  // -0.0 -> +0.0 so float bits are monotonic as uint
}

// ---------------- K0: sum of squares per point ----------------
__global__ __launch_bounds__(256) void k_sump(const float* __restrict__ pts,
                                              float* __restrict__ sump) {
  int g = blockIdx.x * 256 + threadIdx.x;  // over B*N
  float x = pts[g * 3 + 0], y = pts[g * 3 + 1], z = pts[g * 3 + 2];
  sump[g] = rn_sq3(x, y, z);
}

// ---------------- K1: furthest point sampling (1 block / batch) ----------------
// 512 threads, 16 points per thread held in registers.
__global__ __launch_bounds__(512) void k_fps(const float* __restrict__ pts,
                                             int* __restrict__ fps_idx) {
  const int b = blockIdx.x;
  const int tid = threadIdx.x;
  const int lane = tid & 63, wid = tid >> 6;
  const float* P = pts + (size_t)b * Nq * 3;

  __shared__ unsigned long long wkeys[8];
  __shared__ unsigned int bestp_sh;
  __shared__ float bx_sh, by_sh, bz_sh;

  float px[16], py[16], pz[16], dd[16];
#pragma unroll
  for (int k = 0; k < 16; k++) {
    int p = k * 512 + tid;
    px[k] = P[p * 3 + 0];
    py[k] = P[p * 3 + 1];
    pz[k] = P[p * 3 + 2];
  }
  // d0 = dist to point 0, fused with local argmax
  float qx = P[0], qy = P[1], qz = P[2];
  unsigned long long lbest = 0ull;
#pragma unroll
  for (int k = 0; k < 16; k++) {
    int p = k * 512 + tid;
    float d = rn_sq3(__fsub_rn(px[k], qx), __fsub_rn(py[k], qy), __fsub_rn(pz[k], qz));
    dd[k] = d;
    unsigned long long key =
        ((unsigned long long)__float_as_uint(d) << 32) | (unsigned int)(~(unsigned int)p);
    lbest = key > lbest ? key : lbest;
  }
  if (tid == 0) fps_idx[b * NPq] = 0;

  for (int i = 1; i < NPq; i++) {
    // wave-level max reduce of packed (dist, ~idx)
    unsigned long long key = lbest;
#pragma unroll
    for (int off = 32; off > 0; off >>= 1) {
      unsigned long long o = __shfl_down(key, off);
      key = o > key ? o : key;
    }
    if (lane == 0) wkeys[wid] = key;
    __syncthreads();
    if (tid == 0) {
      unsigned long long m = wkeys[0];
#pragma unroll
      for (int w = 1; w < 8; w++) m = wkeys[w] > m ? wkeys[w] : m;
      unsigned int p = ~(unsigned int)(m & 0xFFFFFFFFull);
      bestp_sh = p;
      fps_idx[b * NPq + i] = (int)p;
    }
    __syncthreads();
    unsigned int bp = bestp_sh;
    if ((bp & 511u) == (unsigned int)tid) {
      int k = bp >> 9;
      bx_sh = px[k]; by_sh = py[k]; bz_sh = pz[k];
    }
    __syncthreads();
    float cx = bx_sh, cy = by_sh, cz = bz_sh;
    // fused min-update + local argmax for next round
    lbest = 0ull;
#pragma unroll
    for (int k = 0; k < 16; k++) {
      float d = rn_sq3(__fsub_rn(px[k], cx), __fsub_rn(py[k], cy), __fsub_rn(pz[k], cz));
      float nd = fminf(dd[k], d);
      dd[k] = nd;
      int p = k * 512 + tid;
      unsigned long long kk =
          ((unsigned long long)__float_as_uint(nd) << 32) | (unsigned int)(~(unsigned int)p);
      lbest = kk > lbest ? kk : lbest;
    }
  }
}

// ---------------- K1b: gather sampled coords + their sum-of-squares ----------------
__global__ __launch_bounds__(256) void k_gatherq(const float* __restrict__ pts,
                                                 const float* __restrict__ sump,
                                                 const int* __restrict__ fps_idx,
                                                 float* __restrict__ xyzq,
                                                 float* __restrict__ sumq) {
  int g = blockIdx.x * 256 + threadIdx.x;  // over B*NP
  int b = g >> 11;
  int idx = fps_idx[g];
  int src = b * Nq + idx;
  xyzq[g * 3 + 0] = pts[src * 3 + 0];
  xyzq[g * 3 + 1] = pts[src * 3 + 1];
  xyzq[g * 3 + 2] = pts[src * 3 + 2];
  sumq[g] = sump[src];  // bitwise-identical to ref's sum(xyz_q**2)
}

// ---------------- K2: kNN top-17 per query + grouped mean-pool ----------------
// one block (256 thr) per query; distance row lives in LDS; 17 rounds of argmin.
__global__ __launch_bounds__(256) void k_knn_group(const float* __restrict__ pts,
                                                   const float* __restrict__ sump,
                                                   const float* __restrict__ xyzq,
                                                   const float* __restrict__ sumq,
                                                   const float* __restrict__ feats,
                                                   float* __restrict__ coarse_t) {
  const int blk = blockIdx.x;            // over B*NP
  const int b = blk >> 11;
  const int tid = threadIdx.x;
  const int lane = tid & 63, wid = tid >> 6;
  const float* P = pts + (size_t)b * Nq * 3;
  const float* SP = sump + (size_t)b * Nq;

  __shared__ float sq_lds[Nq];
  __shared__ unsigned long long wkeys[4];
  __shared__ int sel[KSEL];

  float qx = xyzq[blk * 3 + 0], qy = xyzq[blk * 3 + 1], qz = xyzq[blk * 3 + 2];
  float sq_ = sumq[blk];

#pragma unroll
  for (int k = 0; k < 32; k++) {
    int p = k * 256 + tid;
    float x = P[p * 3 + 0], y = P[p * 3 + 1], z = P[p * 3 + 2];
    sq_lds[p] = sq_expand(qx, qy, qz, sq_, x, y, z, SP[p]);
  }
  __syncthreads();

  for (int r = 0; r < KSEL; r++) {
    unsigned long long best = ~0ull;
#pragma unroll
    for (int k = 0; k < 32; k++) {
      int p = k * 256 + tid;
      unsigned long long key =
          ((unsigned long long)__float_as_uint(sq_lds[p]) << 32) | (unsigned int)p;
      best = key < best ? key : best;
    }
#pragma unroll
    for (int off = 32; off > 0; off >>= 1) {
      unsigned long long o = __shfl_down(best, off);
      best = o < best ? o : best;
    }
    if (lane == 0) wkeys[wid] = best;
    __syncthreads();
    if (tid == 0) {
      unsigned long long m = wkeys[0];
      m = wkeys[1] < m ? wkeys[1] : m;
      m = wkeys[2] < m ? wkeys[2] : m;
      m = wkeys[3] < m ? wkeys[3] : m;
      int p = (int)(unsigned int)(m & 0xFFFFFFFFull);
      sel[r] = p;
      sq_lds[p] = __uint_as_float(0x7f800000u);  // mask with +inf
    }
    __syncthreads();
  }

  // grouped mean over neighbors sel[1..16] (self at sel[0] dropped)
  if (tid < Cq) {
    const float* F = feats + ((size_t)(b * Cq + tid)) * Nq;
    float acc = 0.0f;
#pragma unroll
    for (int j = 1; j < KSEL; j++) acc += F[sel[j]];
    coarse_t[(size_t)blk * Cq + tid] = acc * (1.0f / 16.0f);
  }
}

// ---------------- K3: three_nn (top-3 queries per point) + weights ----------------
// one wave per point, 4 waves per block.
__device__ __forceinline__ void merge3(unsigned long long& a0, unsigned long long& a1,
                                       unsigned long long& a2, unsigned long long b0,
                                       unsigned long long b1, unsigned long long b2) {
  unsigned long long lo1 = a0 < b0 ? a0 : b0;
  unsigned long long hi1 = a0 < b0 ? b0 : a0;
  unsigned long long lo2 = a1 < b1 ? a1 : b1;
  unsigned long long hi2 = a1 < b1 ? b1 : a1;
  unsigned long long lo3 = a2 < b2 ? a2 : b2;
  unsigned long long c1 = hi1 < lo2 ? hi1 : lo2;
  unsigned long long m1 = hi1 < lo2 ? lo2 : hi1;
  unsigned long long m2 = hi2 < lo3 ? hi2 : lo3;
  a0 = lo1;
  a1 = c1;
  a2 = m1 < m2 ? m1 : m2;
}

__global__ __launch_bounds__(256) void k_three(const float* __restrict__ pts,
                                               const float* __restrict__ sump,
                                               const float* __restrict__ xyzq,
                                               const float* __restrict__ sumq,
                                               int* __restrict__ i0, int* __restrict__ i1,
                                               int* __restrict__ i2, float* __restrict__ w0,
                                               float* __restrict__ w1, float* __restrict__ w2) {
  const int wid = threadIdx.x >> 6, lane = threadIdx.x & 63;
  const int n = blockIdx.x * 4 + wid;  // global over B*N
  const int b = n >> 13;
  float px = pts[n * 3 + 0], py = pts[n * 3 + 1], pz = pts[n * 3 + 2];
  float sp = sump[n];
  const float* XQ = xyzq + (size_t)b * NPq * 3;
  const float* SQ = sumq + (size_t)b * NPq;

  unsigned long long k0 = ~0ull, k1 = ~0ull, k2 = ~0ull;
#pragma unroll 4
  for (int j = 0; j < 32; j++) {
    int q = lane + j * 64;
    float v = sq_expand(XQ[q * 3 + 0], XQ[q * 3 + 1], XQ[q * 3 + 2], SQ[q], px, py, pz, sp);
    unsigned long long key = ((unsigned long long)__float_as_uint(v) << 32) | (unsigned int)q;
    if (key < k2) {
      if (key < k1) {
        k2 = k1;
        if (key < k0) { k1 = k0; k0 = key; } else { k1 = key; }
      } else {
        k2 = key;
      }
    }
  }
#pragma unroll
  for (int off = 32; off > 0; off >>= 1) {
    unsigned long long o0 = __shfl_down(k0, off);
    unsigned long long o1 = __shfl_down(k1, off);
    unsigned long long o2 = __shfl_down(k2, off);
    merge3(k0, k1, k2, o0, o1, o2);
  }
  if (lane == 0) {
    float v0 = __uint_as_float((unsigned int)(k0 >> 32));
    float v1 = __uint_as_float((unsigned int)(k1 >> 32));
    float v2 = __uint_as_float((unsigned int)(k2 >> 32));
    float d0 = fmaxf(v0, 1e-10f), d1 = fmaxf(v1, 1e-10f), d2 = fmaxf(v2, 1e-10f);
    float inv0 = 1.0f / (d0 + 1e-8f);
    float inv1 = 1.0f / (d1 + 1e-8f);
    float inv2 = 1.0f / (d2 + 1e-8f);
    float s = inv0 + inv1 + inv2;
    i0[n] = (int)(unsigned int)(k0 & 0xFFFFFFFFull);
    i1[n] = (int)(unsigned int)(k1 & 0xFFFFFFFFull);
    i2[n] = (int)(unsigned int)(k2 & 0xFFFFFFFFull);
    w0[n] = inv0 / s;
    w1[n] = inv1 / s;
    w2[n] = inv2 / s;
  }
}

// ---------------- K4: inverse-distance interpolation ----------------
__global__ __launch_bounds__(256) void k_interp(const float* __restrict__ coarse_t,
                                                const int* __restrict__ i0,
                                                const int* __restrict__ i1,
                                                const int* __restrict__ i2,
                                                const float* __restrict__ w0,
                                                const float* __restrict__ w1,
                                                const float* __restrict__ w2,
                                                float* __restrict__ out) {
  int g = blockIdx.x * 256 + threadIdx.x;  // over B*N
  int b = g >> 13, n = g & (Nq - 1);
  int a0 = i0[g], a1 = i1[g], a2 = i2[g];
  float u0 = w0[g], u1 = w1[g], u2 = w2[g];
  const float4* r0 = (const float4*)(coarse_t + ((size_t)b * NPq + a0) * Cq);
  const float4* r1 = (const float4*)(coarse_t + ((size_t)b * NPq + a1) * Cq);
  const float4* r2 = (const float4*)(coarse_t + ((size_t)b * NPq + a2) * Cq);
  float* O = out + (size_t)b * Cq * Nq + n;
#pragma unroll 4
  for (int cq = 0; cq < Cq / 4; cq++) {
    float4 f0 = r0[cq], f1 = r1[cq], f2 = r2[cq];
    float o0 = u0 * f0.x + u1 * f1.x + u2 * f2.x;
    float o1 = u0 * f0.y + u1 * f1.y + u2 * f2.y;
    float o2 = u0 * f0.z + u1 * f1.z + u2 * f2.z;
    float o3 = u0 * f0.w + u1 * f1.w + u2 * f2.w;
    O[(size_t)(cq * 4 + 0) * Nq] = o0;
    O[(size_t)(cq * 4 + 1) * Nq] = o1;
    O[(size_t)(cq * 4 + 2) * Nq] = o2;
    O[(size_t)(cq * 4 + 3) * Nq] = o3;
  }
}

// ---------------- launch ----------------
extern "C" void kernel_launch(void* const* d_in, const int* in_sizes, int n_in,
                              void* d_out, int out_size, void* d_ws, size_t ws_size,
                              hipStream_t stream) {
  const float* pts = (const float*)d_in[0];    // [B,N,3]
  const float* feats = (const float*)d_in[1];  // [B,C,N]
  float* out = (float*)d_out;                  // [B,C,N]

  char* ws = (char*)d_ws;
  size_t off = 0;
  auto alloc = [&](size_t bytes) {
    void* p = ws + off;
    off += (bytes + 255) & ~(size_t)255;
    return p;
  };
  float* sump = (float*)alloc((size_t)Bq * Nq * 4);
  int* fps_idx = (int*)alloc((size_t)Bq * NPq * 4);
  float* xyzq = (float*)alloc((size_t)Bq * NPq * 3 * 4);
  float* sumq = (float*)alloc((size_t)Bq * NPq * 4);
  float* coarse_t = (float*)alloc((size_t)Bq * NPq * Cq * 4);
  int* i0 = (int*)alloc((size_t)Bq * Nq * 4);
  int* i1 = (int*)alloc((size_t)Bq * Nq * 4);
  int* i2 = (int*)alloc((size_t)Bq * Nq * 4);
  float* w0 = (float*)alloc((size_t)Bq * Nq * 4);
  float* w1 = (float*)alloc((size_t)Bq * Nq * 4);
  float* w2 = (float*)alloc((size_t)Bq * Nq * 4);

  k_sump<<<(Bq * Nq) / 256, 256, 0, stream>>>(pts, sump);
  k_fps<<<Bq, 512, 0, stream>>>(pts, fps_idx);
  k_gatherq<<<(Bq * NPq) / 256, 256, 0, stream>>>(pts, sump, fps_idx, xyzq, sumq);
  k_knn_group<<<Bq * NPq, 256, 0, stream>>>(pts, sump, xyzq, sumq, feats, coarse_t);
  k_three<<<(Bq * Nq) / 4, 256, 0, stream>>>(pts, sump, xyzq, sumq, i0, i1, i2, w0, w1, w2);
  k_interp<<<(Bq * Nq) / 256, 256, 0, stream>>>(coarse_t, i0, i1, i2, w0, w1, w2, out);
}

// Round 2
// 2769.852 us; speedup vs baseline: 1.0432x; 1.0432x over previous
//
#include <hip/hip_runtime.h>
#include <cstdint>
#include <cstddef>

#define Bq   4
#define Nq   8192
#define Cq   128
#define NPq  2048
#define NSq  16
#define KSEL 17

// --- numerics helpers (rn ops block fma-contraction; must match numpy fp32 order) ---
__device__ __forceinline__ float rn_sq3(float x, float y, float z) {
  return __fadd_rn(__fadd_rn(__fmul_rn(x, x), __fmul_rn(y, y)), __fmul_rn(z, z));
}

// expanded-form squared distance, matching ref: max(sumq + sump - 2*dot, 0)
__device__ __forceinline__ float sq_expand(float qx, float qy, float qz, float sq_,
                                           float px, float py, float pz, float sp_) {
  float dot = __fadd_rn(__fadd_rn(__fmul_rn(qx, px), __fmul_rn(qy, py)), __fmul_rn(qz, pz));
  float v = __fsub_rn(__fadd_rn(sq_, sp_), __fmul_rn(2.0f, dot));
  v = fmaxf(v, 0.0f);
  return __fadd_rn(v, 0.0f);  // -0.0 -> +0.0 so float bits are monotonic as uint
}

// ---------------- K0: sum of squares per point ----------------
__global__ __launch_bounds__(256) void k_sump(const float* __restrict__ pts,
                                              float* __restrict__ sump) {
  int g = blockIdx.x * 256 + threadIdx.x;  // over B*N
  float x = pts[g * 3 + 0], y = pts[g * 3 + 1], z = pts[g * 3 + 2];
  sump[g] = rn_sq3(x, y, z);
}

// ---------------- K1: furthest point sampling (1 block / batch) ----------------
// 512 threads, 16 points/thread in registers. ONE barrier per iteration:
//  - wave shuffle-max of packed (dist_bits<<32)|~idx
//  - lane0 -> wkeys[i&1][wid]  (parity double-buffer kills the extra barrier)
//  - barrier; ALL threads scan the 8 keys (LDS broadcast, no serial tid0 phase)
//  - winner coords re-loaded from global (L1/L2 hit), no LDS coord broadcast
__global__ __launch_bounds__(512) void k_fps(const float* __restrict__ pts,
                                             int* __restrict__ fps_idx) {
  const int b = blockIdx.x;
  const int tid = threadIdx.x;
  const int lane = tid & 63, wid = tid >> 6;
  const float* P = pts + (size_t)b * Nq * 3;

  __shared__ unsigned long long wkeys[2][8];

  float px[16], py[16], pz[16], dd[16];
#pragma unroll
  for (int k = 0; k < 16; k++) {
    int p = k * 512 + tid;
    px[k] = P[p * 3 + 0];
    py[k] = P[p * 3 + 1];
    pz[k] = P[p * 3 + 2];
  }
  // d0 = dist to point 0, fused with local argmax (bk = element slot, inline-const)
  float qx = P[0], qy = P[1], qz = P[2];
  float bd = -1.0f;
  int bk = 0;
#pragma unroll
  for (int k = 0; k < 16; k++) {
    float d = rn_sq3(__fsub_rn(px[k], qx), __fsub_rn(py[k], qy), __fsub_rn(pz[k], qz));
    dd[k] = d;
    if (d > bd) { bd = d; bk = k; }
  }
  int bp = (bk << 9) + tid;
  if (tid == 0) fps_idx[b * NPq] = 0;

  for (int i = 1; i < NPq; i++) {
    // pack (dist, ~idx): max-reduce ties to smallest index, like jnp.argmax
    unsigned long long key =
        ((unsigned long long)__float_as_uint(bd) << 32) | (unsigned int)(~(unsigned int)bp);
#pragma unroll
    for (int off = 32; off > 0; off >>= 1) {
      unsigned long long o = __shfl_down(key, off);
      key = o > key ? o : key;
    }
    if (lane == 0) wkeys[i & 1][wid] = key;
    __syncthreads();

    // all threads redundantly scan the 8 wave keys (LDS broadcast reads)
    unsigned long long m = wkeys[i & 1][0];
#pragma unroll
    for (int w = 1; w < 8; w++) {
      unsigned long long t = wkeys[i & 1][w];
      m = t > m ? t : m;
    }
    unsigned int p = ~(unsigned int)m;
    if (tid == 0) fps_idx[b * NPq + i] = (int)p;

    // winner coords straight from global (same addr per wave -> 1 request, L1/L2 hit)
    const float* cp = P + 3u * p;
    float cx = cp[0], cy = cp[1], cz = cp[2];

    // fused min-update + local argmax for next round
    bd = -1.0f;
    bk = 0;
#pragma unroll
    for (int k = 0; k < 16; k++) {
      float d = rn_sq3(__fsub_rn(px[k], cx), __fsub_rn(py[k], cy), __fsub_rn(pz[k], cz));
      float nd = fminf(dd[k], d);
      dd[k] = nd;
      if (nd > bd) { bd = nd; bk = k; }
    }
    bp = (bk << 9) + tid;
  }
}

// ---------------- K1b: gather sampled coords + their sum-of-squares ----------------
__global__ __launch_bounds__(256) void k_gatherq(const float* __restrict__ pts,
                                                 const float* __restrict__ sump,
                                                 const int* __restrict__ fps_idx,
                                                 float* __restrict__ xyzq,
                                                 float* __restrict__ sumq) {
  int g = blockIdx.x * 256 + threadIdx.x;  // over B*NP
  int b = g >> 11;
  int idx = fps_idx[g];
  int src = b * Nq + idx;
  xyzq[g * 3 + 0] = pts[src * 3 + 0];
  xyzq[g * 3 + 1] = pts[src * 3 + 1];
  xyzq[g * 3 + 2] = pts[src * 3 + 2];
  sumq[g] = sump[src];  // bitwise-identical to ref's sum(xyz_q**2)
}

// ---------------- K2: kNN top-17 per query + grouped mean-pool ----------------
// one block (256 thr) per query; distance row lives in LDS; 17 rounds of argmin.
__global__ __launch_bounds__(256) void k_knn_group(const float* __restrict__ pts,
                                                   const float* __restrict__ sump,
                                                   const float* __restrict__ xyzq,
                                                   const float* __restrict__ sumq,
                                                   const float* __restrict__ feats,
                                                   float* __restrict__ coarse_t) {
  const int blk = blockIdx.x;            // over B*NP
  const int b = blk >> 11;
  const int tid = threadIdx.x;
  const int lane = tid & 63, wid = tid >> 6;
  const float* P = pts + (size_t)b * Nq * 3;
  const float* SP = sump + (size_t)b * Nq;

  __shared__ float sq_lds[Nq];
  __shared__ unsigned long long wkeys[4];
  __shared__ int sel[KSEL];

  float qx = xyzq[blk * 3 + 0], qy = xyzq[blk * 3 + 1], qz = xyzq[blk * 3 + 2];
  float sq_ = sumq[blk];

#pragma unroll
  for (int k = 0; k < 32; k++) {
    int p = k * 256 + tid;
    float x = P[p * 3 + 0], y = P[p * 3 + 1], z = P[p * 3 + 2];
    sq_lds[p] = sq_expand(qx, qy, qz, sq_, x, y, z, SP[p]);
  }
  __syncthreads();

  for (int r = 0; r < KSEL; r++) {
    unsigned long long best = ~0ull;
#pragma unroll
    for (int k = 0; k < 32; k++) {
      int p = k * 256 + tid;
      unsigned long long key =
          ((unsigned long long)__float_as_uint(sq_lds[p]) << 32) | (unsigned int)p;
      best = key < best ? key : best;
    }
#pragma unroll
    for (int off = 32; off > 0; off >>= 1) {
      unsigned long long o = __shfl_down(best, off);
      best = o < best ? o : best;
    }
    if (lane == 0) wkeys[wid] = best;
    __syncthreads();
    if (tid == 0) {
      unsigned long long m = wkeys[0];
      m = wkeys[1] < m ? wkeys[1] : m;
      m = wkeys[2] < m ? wkeys[2] : m;
      m = wkeys[3] < m ? wkeys[3] : m;
      int p = (int)(unsigned int)(m & 0xFFFFFFFFull);
      sel[r] = p;
      sq_lds[p] = __uint_as_float(0x7f800000u);  // mask with +inf
    }
    __syncthreads();
  }

  // grouped mean over neighbors sel[1..16] (self at sel[0] dropped)
  if (tid < Cq) {
    const float* F = feats + ((size_t)(b * Cq + tid)) * Nq;
    float acc = 0.0f;
#pragma unroll
    for (int j = 1; j < KSEL; j++) acc += F[sel[j]];
    coarse_t[(size_t)blk * Cq + tid] = acc * (1.0f / 16.0f);
  }
}

// ---------------- K3: three_nn (top-3 queries per point) + weights ----------------
// one wave per point, 4 waves per block.
__device__ __forceinline__ void merge3(unsigned long long& a0, unsigned long long& a1,
                                       unsigned long long& a2, unsigned long long b0,
                                       unsigned long long b1, unsigned long long b2) {
  unsigned long long lo1 = a0 < b0 ? a0 : b0;
  unsigned long long hi1 = a0 < b0 ? b0 : a0;
  unsigned long long lo2 = a1 < b1 ? a1 : b1;
  unsigned long long hi2 = a1 < b1 ? b1 : a1;
  unsigned long long lo3 = a2 < b2 ? a2 : b2;
  unsigned long long c1 = hi1 < lo2 ? hi1 : lo2;
  unsigned long long m1 = hi1 < lo2 ? lo2 : hi1;
  unsigned long long m2 = hi2 < lo3 ? hi2 : lo3;
  a0 = lo1;
  a1 = c1;
  a2 = m1 < m2 ? m1 : m2;
}

__global__ __launch_bounds__(256) void k_three(const float* __restrict__ pts,
                                               const float* __restrict__ sump,
                                               const float* __restrict__ xyzq,
                                               const float* __restrict__ sumq,
                                               int* __restrict__ i0, int* __restrict__ i1,
                                               int* __restrict__ i2, float* __restrict__ w0,
                                               float* __restrict__ w1, float* __restrict__ w2) {
  const int wid = threadIdx.x >> 6, lane = threadIdx.x & 63;
  const int n = blockIdx.x * 4 + wid;  // global over B*N
  const int b = n >> 13;
  float px = pts[n * 3 + 0], py = pts[n * 3 + 1], pz = pts[n * 3 + 2];
  float sp = sump[n];
  const float* XQ = xyzq + (size_t)b * NPq * 3;
  const float* SQ = sumq + (size_t)b * NPq;

  unsigned long long k0 = ~0ull, k1 = ~0ull, k2 = ~0ull;
#pragma unroll 4
  for (int j = 0; j < 32; j++) {
    int q = lane + j * 64;
    float v = sq_expand(XQ[q * 3 + 0], XQ[q * 3 + 1], XQ[q * 3 + 2], SQ[q], px, py, pz, sp);
    unsigned long long key = ((unsigned long long)__float_as_uint(v) << 32) | (unsigned int)q;
    if (key < k2) {
      if (key < k1) {
        k2 = k1;
        if (key < k0) { k1 = k0; k0 = key; } else { k1 = key; }
      } else {
        k2 = key;
      }
    }
  }
#pragma unroll
  for (int off = 32; off > 0; off >>= 1) {
    unsigned long long o0 = __shfl_down(k0, off);
    unsigned long long o1 = __shfl_down(k1, off);
    unsigned long long o2 = __shfl_down(k2, off);
    merge3(k0, k1, k2, o0, o1, o2);
  }
  if (lane == 0) {
    float v0 = __uint_as_float((unsigned int)(k0 >> 32));
    float v1 = __uint_as_float((unsigned int)(k1 >> 32));
    float v2 = __uint_as_float((unsigned int)(k2 >> 32));
    float d0 = fmaxf(v0, 1e-10f), d1 = fmaxf(v1, 1e-10f), d2 = fmaxf(v2, 1e-10f);
    float inv0 = 1.0f / (d0 + 1e-8f);
    float inv1 = 1.0f / (d1 + 1e-8f);
    float inv2 = 1.0f / (d2 + 1e-8f);
    float s = inv0 + inv1 + inv2;
    i0[n] = (int)(unsigned int)(k0 & 0xFFFFFFFFull);
    i1[n] = (int)(unsigned int)(k1 & 0xFFFFFFFFull);
    i2[n] = (int)(unsigned int)(k2 & 0xFFFFFFFFull);
    w0[n] = inv0 / s;
    w1[n] = inv1 / s;
    w2[n] = inv2 / s;
  }
}

// ---------------- K4: inverse-distance interpolation ----------------
__global__ __launch_bounds__(256) void k_interp(const float* __restrict__ coarse_t,
                                                const int* __restrict__ i0,
                                                const int* __restrict__ i1,
                                                const int* __restrict__ i2,
                                                const float* __restrict__ w0,
                                                const float* __restrict__ w1,
                                                const float* __restrict__ w2,
                                                float* __restrict__ out) {
  int g = blockIdx.x * 256 + threadIdx.x;  // over B*N
  int b = g >> 13, n = g & (Nq - 1);
  int a0 = i0[g], a1 = i1[g], a2 = i2[g];
  float u0 = w0[g], u1 = w1[g], u2 = w2[g];
  const float4* r0 = (const float4*)(coarse_t + ((size_t)b * NPq + a0) * Cq);
  const float4* r1 = (const float4*)(coarse_t + ((size_t)b * NPq + a1) * Cq);
  const float4* r2 = (const float4*)(coarse_t + ((size_t)b * NPq + a2) * Cq);
  float* O = out + (size_t)b * Cq * Nq + n;
#pragma unroll 4
  for (int cq = 0; cq < Cq / 4; cq++) {
    float4 f0 = r0[cq], f1 = r1[cq], f2 = r2[cq];
    float o0 = u0 * f0.x + u1 * f1.x + u2 * f2.x;
    float o1 = u0 * f0.y + u1 * f1.y + u2 * f2.y;
    float o2 = u0 * f0.z + u1 * f1.z + u2 * f2.z;
    float o3 = u0 * f0.w + u1 * f1.w + u2 * f2.w;
    O[(size_t)(cq * 4 + 0) * Nq] = o0;
    O[(size_t)(cq * 4 + 1) * Nq] = o1;
    O[(size_t)(cq * 4 + 2) * Nq] = o2;
    O[(size_t)(cq * 4 + 3) * Nq] = o3;
  }
}

// ---------------- launch ----------------
extern "C" void kernel_launch(void* const* d_in, const int* in_sizes, int n_in,
                              void* d_out, int out_size, void* d_ws, size_t ws_size,
                              hipStream_t stream) {
  const float* pts = (const float*)d_in[0];    // [B,N,3]
  const float* feats = (const float*)d_in[1];  // [B,C,N]
  float* out = (float*)d_out;                  // [B,C,N]

  char* ws = (char*)d_ws;
  size_t off = 0;
  auto alloc = [&](size_t bytes) {
    void* p = ws + off;
    off += (bytes + 255) & ~(size_t)255;
    return p;
  };
  float* sump = (float*)alloc((size_t)Bq * Nq * 4);
  int* fps_idx = (int*)alloc((size_t)Bq * NPq * 4);
  float* xyzq = (float*)alloc((size_t)Bq * NPq * 3 * 4);
  float* sumq = (float*)alloc((size_t)Bq * NPq * 4);
  float* coarse_t = (float*)alloc((size_t)Bq * NPq * Cq * 4);
  int* i0 = (int*)alloc((size_t)Bq * Nq * 4);
  int* i1 = (int*)alloc((size_t)Bq * Nq * 4);
  int* i2 = (int*)alloc((size_t)Bq * Nq * 4);
  float* w0 = (float*)alloc((size_t)Bq * Nq * 4);
  float* w1 = (float*)alloc((size_t)Bq * Nq * 4);
  float* w2 = (float*)alloc((size_t)Bq * Nq * 4);

  k_sump<<<(Bq * Nq) / 256, 256, 0, stream>>>(pts, sump);
  k_fps<<<Bq, 512, 0, stream>>>(pts, fps_idx);
  k_gatherq<<<(Bq * NPq) / 256, 256, 0, stream>>>(pts, sump, fps_idx, xyzq, sumq);
  k_knn_group<<<Bq * NPq, 256, 0, stream>>>(pts, sump, xyzq, sumq, feats, coarse_t);
  k_three<<<(Bq * Nq) / 4, 256, 0, stream>>>(pts, sump, xyzq, sumq, i0, i1, i2, w0, w1, w2);
  k_interp<<<(Bq * Nq) / 256, 256, 0, stream>>>(coarse_t, i0, i1, i2, w0, w1, w2, out);
}

// Round 3
// 2411.824 us; speedup vs baseline: 1.1981x; 1.1484x over previous
//
#include <hip/hip_runtime.h>
#include <cstdint>
#include <cstddef>

#define Bq   4
#define Nq   8192
#define Cq   128
#define NPq  2048
#define KSEL 17

typedef float v2f __attribute__((ext_vector_type(2)));

// --- numerics helpers (rn ops / contract-off block fma fusion; must match numpy fp32 order) ---
__device__ __forceinline__ float rn_sq3(float x, float y, float z) {
  return __fadd_rn(__fadd_rn(__fmul_rn(x, x), __fmul_rn(y, y)), __fmul_rn(z, z));
}

// packed 2-point squared distance, exact rn per-op, order ((dx^2+dy^2)+dz^2)
__device__ __forceinline__ v2f dist2_v2(v2f px, v2f py, v2f pz, float cx, float cy, float cz) {
#pragma clang fp contract(off)
  v2f dx = px - cx;
  v2f dy = py - cy;
  v2f dz = pz - cz;
  v2f s = dx * dx + dy * dy + dz * dz;  // (mul,mul,mul,add,add), left-assoc
  return s;
}

// expanded-form squared distance, matching ref: max(sumq + sump - 2*dot, 0)
__device__ __forceinline__ float sq_expand(float qx, float qy, float qz, float sq_,
                                           float px, float py, float pz, float sp_) {
  float dot = __fadd_rn(__fadd_rn(__fmul_rn(qx, px), __fmul_rn(qy, py)), __fmul_rn(qz, pz));
  float v = __fsub_rn(__fadd_rn(sq_, sp_), __fmul_rn(2.0f, dot));
  v = fmaxf(v, 0.0f);
  return __fadd_rn(v, 0.0f);  // -0.0 -> +0.0 so float bits are monotonic as uint
}

// ---------------- K0: sum of squares per point ----------------
__global__ __launch_bounds__(256) void k_sump(const float* __restrict__ pts,
                                              float* __restrict__ sump) {
  int g = blockIdx.x * 256 + threadIdx.x;  // over B*N
  float x = pts[g * 3 + 0], y = pts[g * 3 + 1], z = pts[g * 3 + 2];
  sump[g] = rn_sq3(x, y, z);
}

// ---------------- K1: furthest point sampling (1 block / batch) ----------------
// 512 threads, 16 CONTIGUOUS points/thread (p = tid*16+k) so lane order == index
// order; packed-f32 distance math; wave argmax via DPP f32-max + ballot (ties ->
// lowest lane -> smallest index, matching jnp.argmax); 1 barrier/iteration with
// parity-buffered per-wave (value,idx) slots.
template <int CTRL, int RM, int BM>
__device__ __forceinline__ float dpp_maxf(float v) {
  int r = __builtin_amdgcn_update_dpp(__float_as_int(v), __float_as_int(v), CTRL, RM, BM, false);
  return fmaxf(v, __int_as_float(r));
}

__global__ __launch_bounds__(512) void k_fps(const float* __restrict__ pts,
                                             int* __restrict__ fps_idx) {
  const int b = blockIdx.x;
  const int tid = threadIdx.x;
  const int lane = tid & 63, wid = tid >> 6;
  const float* P = pts + (size_t)b * Nq * 3;

  __shared__ float sv[2][8];
  __shared__ int spi[2][8];

  v2f px[8], py[8], pz[8], dd[8];
  const int pbase = tid * 16;
#pragma unroll
  for (int j = 0; j < 8; j++) {
    const float2* q2 = (const float2*)(P + (size_t)(pbase + 2 * j) * 3);
    float2 A = q2[0], Bv = q2[1], Cv = q2[2];  // (x0,y0) (z0,x1) (y1,z1)
    v2f tx, ty, tz;
    tx.x = A.x;  tx.y = Bv.y;
    ty.x = A.y;  ty.y = Cv.x;
    tz.x = Bv.x; tz.y = Cv.y;
    px[j] = tx; py[j] = ty; pz[j] = tz;
  }
  float qx = P[0], qy = P[1], qz = P[2];
  float bd = -1.0f;
  int bp = pbase;
#pragma unroll
  for (int j = 0; j < 8; j++) {
    v2f s = dist2_v2(px[j], py[j], pz[j], qx, qy, qz);
    dd[j] = s;
    if (s.x > bd) { bd = s.x; bp = pbase + 2 * j; }
    if (s.y > bd) { bd = s.y; bp = pbase + 2 * j + 1; }
  }
  if (tid == 0) fps_idx[b * NPq] = 0;

  for (int i = 1; i < NPq; i++) {
    // wave max (value only) via DPP: row_shr 1/2/4/8, row_bcast15 (rows 1,3),
    // row_bcast31 (rows 2,3); full max lands in lane 63.
    float wv = bd;
    wv = dpp_maxf<0x111, 0xf, 0xf>(wv);
    wv = dpp_maxf<0x112, 0xf, 0xf>(wv);
    wv = dpp_maxf<0x114, 0xf, 0xf>(wv);
    wv = dpp_maxf<0x118, 0xf, 0xf>(wv);
    wv = dpp_maxf<0x142, 0xa, 0xf>(wv);
    wv = dpp_maxf<0x143, 0xc, 0xf>(wv);
    float wmax = __int_as_float(__builtin_amdgcn_readlane(__float_as_int(wv), 63));
    unsigned long long msk = __ballot(bd == wmax);
    int wl = (int)__ffsll(msk) - 1;      // lowest tied lane = smallest index
    int wbp = __shfl(bp, wl);
    if (lane == 0) { sv[i & 1][wid] = wmax; spi[i & 1][wid] = wbp; }
    __syncthreads();

    // all threads scan the 8 wave slots; strict > keeps earliest wave on ties
    float bv = sv[i & 1][0];
    int bip = spi[i & 1][0];
#pragma unroll
    for (int w = 1; w < 8; w++) {
      float tv = sv[i & 1][w];
      bool t = tv > bv;
      bv = t ? tv : bv;
      bip = t ? spi[i & 1][w] : bip;
    }
    if (tid == 0) fps_idx[b * NPq + i] = bip;

    const float* cp = P + (size_t)bip * 3;
    float cx = cp[0], cy = cp[1], cz = cp[2];

    bd = -1.0f;
    bp = pbase;
#pragma unroll
    for (int j = 0; j < 8; j++) {
      v2f s = dist2_v2(px[j], py[j], pz[j], cx, cy, cz);
      v2f nd;
      nd.x = fminf(dd[j].x, s.x);
      nd.y = fminf(dd[j].y, s.y);
      dd[j] = nd;
      if (nd.x > bd) { bd = nd.x; bp = pbase + 2 * j; }
      if (nd.y > bd) { bd = nd.y; bp = pbase + 2 * j + 1; }
    }
  }
}

// ---------------- K1b: gather sampled coords + sum-of-squares (+SoA copies) ----------------
__global__ __launch_bounds__(256) void k_gatherq(const float* __restrict__ pts,
                                                 const float* __restrict__ sump,
                                                 const int* __restrict__ fps_idx,
                                                 float* __restrict__ xyzq,
                                                 float* __restrict__ sumq,
                                                 float* __restrict__ xqs,
                                                 float* __restrict__ yqs,
                                                 float* __restrict__ zqs) {
  int g = blockIdx.x * 256 + threadIdx.x;  // over B*NP
  int b = g >> 11;
  int idx = fps_idx[g];
  int src = b * Nq + idx;
  float x = pts[src * 3 + 0], y = pts[src * 3 + 1], z = pts[src * 3 + 2];
  xyzq[g * 3 + 0] = x;
  xyzq[g * 3 + 1] = y;
  xyzq[g * 3 + 2] = z;
  xqs[g] = x; yqs[g] = y; zqs[g] = z;
  sumq[g] = sump[src];  // bitwise-identical to ref's sum(xyz_q**2)
}

// ---------------- K2: kNN top-17 per query + grouped mean-pool ----------------
// one block (256 thr) per query. Per-thread min key cached in a register; per
// round only the removed point's owner rescans its 32 entries. 1 barrier/round.
__global__ __launch_bounds__(256) void k_knn_group(const float* __restrict__ pts,
                                                   const float* __restrict__ sump,
                                                   const float* __restrict__ xyzq,
                                                   const float* __restrict__ sumq,
                                                   const float* __restrict__ feats,
                                                   float* __restrict__ coarse_t) {
  const int blk = blockIdx.x;  // over B*NP
  const int b = blk >> 11;
  const int tid = threadIdx.x;
  const int lane = tid & 63, wid = tid >> 6;
  const float* P = pts + (size_t)b * Nq * 3;
  const float* SP = sump + (size_t)b * Nq;

  __shared__ float sq_lds[Nq];
  __shared__ unsigned long long wk[2][4];
  __shared__ int sel[KSEL];

  float qx = xyzq[blk * 3 + 0], qy = xyzq[blk * 3 + 1], qz = xyzq[blk * 3 + 2];
  float sq_ = sumq[blk];

  unsigned long long lmin = ~0ull;
#pragma unroll
  for (int k = 0; k < 32; k++) {
    int p = k * 256 + tid;
    float x = P[p * 3 + 0], y = P[p * 3 + 1], z = P[p * 3 + 2];
    float v = sq_expand(qx, qy, qz, sq_, x, y, z, SP[p]);
    sq_lds[p] = v;
    unsigned long long key = ((unsigned long long)__float_as_uint(v) << 32) | (unsigned int)p;
    lmin = key < lmin ? key : lmin;
  }
  // no barrier: each thread only ever touches its own sq_lds entries (p%256==tid)

  for (int r = 0; r < KSEL; r++) {
    unsigned long long key = lmin;
#pragma unroll
    for (int off = 32; off > 0; off >>= 1) {
      unsigned long long o = __shfl_down(key, off);
      key = o < key ? o : key;
    }
    if (lane == 0) wk[r & 1][wid] = key;
    __syncthreads();
    unsigned long long m = wk[r & 1][0];
    m = wk[r & 1][1] < m ? wk[r & 1][1] : m;
    m = wk[r & 1][2] < m ? wk[r & 1][2] : m;
    m = wk[r & 1][3] < m ? wk[r & 1][3] : m;
    int p = (int)(unsigned int)(m & 0xFFFFFFFFull);
    if (tid == 0) sel[r] = p;
    if ((p & 255) == tid) {  // owner removes winner and rebuilds its local min
      sq_lds[p] = __uint_as_float(0x7f800000u);
      lmin = ~0ull;
#pragma unroll
      for (int k = 0; k < 32; k++) {
        int pp = k * 256 + tid;
        unsigned long long kk =
            ((unsigned long long)__float_as_uint(sq_lds[pp]) << 32) | (unsigned int)pp;
        lmin = kk < lmin ? kk : lmin;
      }
    }
  }
  __syncthreads();

  // grouped mean over neighbors sel[1..16] (self at sel[0] dropped)
  if (tid < Cq) {
    const float* F = feats + ((size_t)(b * Cq + tid)) * Nq;
    float acc = 0.0f;
#pragma unroll
    for (int j = 1; j < KSEL; j++) acc += F[sel[j]];
    coarse_t[(size_t)blk * Cq + tid] = acc * (1.0f / 16.0f);
  }
}

// ---------------- K3: three_nn (top-3 queries per point) + weights ----------------
__device__ __forceinline__ void merge3(unsigned long long& a0, unsigned long long& a1,
                                       unsigned long long& a2, unsigned long long b0,
                                       unsigned long long b1, unsigned long long b2) {
  unsigned long long lo1 = a0 < b0 ? a0 : b0;
  unsigned long long hi1 = a0 < b0 ? b0 : a0;
  unsigned long long lo2 = a1 < b1 ? a1 : b1;
  unsigned long long hi2 = a1 < b1 ? b1 : a1;
  unsigned long long lo3 = a2 < b2 ? a2 : b2;
  unsigned long long c1 = hi1 < lo2 ? hi1 : lo2;
  unsigned long long m1 = hi1 < lo2 ? lo2 : hi1;
  unsigned long long m2 = hi2 < lo3 ? hi2 : lo3;
  a0 = lo1;
  a1 = c1;
  a2 = m1 < m2 ? m1 : m2;
}

__global__ __launch_bounds__(256) void k_three(const float* __restrict__ pts,
                                               const float* __restrict__ sump,
                                               const float* __restrict__ xqs,
                                               const float* __restrict__ yqs,
                                               const float* __restrict__ zqs,
                                               const float* __restrict__ sumq,
                                               int* __restrict__ i0, int* __restrict__ i1,
                                               int* __restrict__ i2, float* __restrict__ w0,
                                               float* __restrict__ w1, float* __restrict__ w2) {
  const int wid = threadIdx.x >> 6, lane = threadIdx.x & 63;
  const int n = blockIdx.x * 4 + wid;  // global over B*N
  const int b = n >> 13;
  float px = pts[n * 3 + 0], py = pts[n * 3 + 1], pz = pts[n * 3 + 2];
  float sp = sump[n];
  const float* QX = xqs + (size_t)b * NPq;
  const float* QY = yqs + (size_t)b * NPq;
  const float* QZ = zqs + (size_t)b * NPq;
  const float* SQ = sumq + (size_t)b * NPq;

  unsigned long long k0 = ~0ull, k1 = ~0ull, k2 = ~0ull;
#pragma unroll 4
  for (int j = 0; j < 32; j++) {
    int q = lane + j * 64;
    float v = sq_expand(QX[q], QY[q], QZ[q], SQ[q], px, py, pz, sp);
    unsigned long long key = ((unsigned long long)__float_as_uint(v) << 32) | (unsigned int)q;
    if (key < k2) {
      if (key < k1) {
        k2 = k1;
        if (key < k0) { k1 = k0; k0 = key; } else { k1 = key; }
      } else {
        k2 = key;
      }
    }
  }
#pragma unroll
  for (int off = 32; off > 0; off >>= 1) {
    unsigned long long o0 = __shfl_down(k0, off);
    unsigned long long o1 = __shfl_down(k1, off);
    unsigned long long o2 = __shfl_down(k2, off);
    merge3(k0, k1, k2, o0, o1, o2);
  }
  if (lane == 0) {
    float v0 = __uint_as_float((unsigned int)(k0 >> 32));
    float v1 = __uint_as_float((unsigned int)(k1 >> 32));
    float v2 = __uint_as_float((unsigned int)(k2 >> 32));
    float d0 = fmaxf(v0, 1e-10f), d1 = fmaxf(v1, 1e-10f), d2 = fmaxf(v2, 1e-10f);
    float inv0 = 1.0f / (d0 + 1e-8f);
    float inv1 = 1.0f / (d1 + 1e-8f);
    float inv2 = 1.0f / (d2 + 1e-8f);
    float s = inv0 + inv1 + inv2;
    i0[n] = (int)(unsigned int)(k0 & 0xFFFFFFFFull);
    i1[n] = (int)(unsigned int)(k1 & 0xFFFFFFFFull);
    i2[n] = (int)(unsigned int)(k2 & 0xFFFFFFFFull);
    w0[n] = inv0 / s;
    w1[n] = inv1 / s;
    w2[n] = inv2 / s;
  }
}

// ---------------- K4: inverse-distance interpolation ----------------
__global__ __launch_bounds__(256) void k_interp(const float* __restrict__ coarse_t,
                                                const int* __restrict__ i0,
                                                const int* __restrict__ i1,
                                                const int* __restrict__ i2,
                                                const float* __restrict__ w0,
                                                const float* __restrict__ w1,
                                                const float* __restrict__ w2,
                                                float* __restrict__ out) {
  int g = blockIdx.x * 256 + threadIdx.x;  // over B*N
  int b = g >> 13, n = g & (Nq - 1);
  int a0 = i0[g], a1 = i1[g], a2 = i2[g];
  float u0 = w0[g], u1 = w1[g], u2 = w2[g];
  const float4* r0 = (const float4*)(coarse_t + ((size_t)b * NPq + a0) * Cq);
  const float4* r1 = (const float4*)(coarse_t + ((size_t)b * NPq + a1) * Cq);
  const float4* r2 = (const float4*)(coarse_t + ((size_t)b * NPq + a2) * Cq);
  float* O = out + (size_t)b * Cq * Nq + n;
#pragma unroll 4
  for (int cq = 0; cq < Cq / 4; cq++) {
    float4 f0 = r0[cq], f1 = r1[cq], f2 = r2[cq];
    float o0 = u0 * f0.x + u1 * f1.x + u2 * f2.x;
    float o1 = u0 * f0.y + u1 * f1.y + u2 * f2.y;
    float o2 = u0 * f0.z + u1 * f1.z + u2 * f2.z;
    float o3 = u0 * f0.w + u1 * f1.w + u2 * f2.w;
    O[(size_t)(cq * 4 + 0) * Nq] = o0;
    O[(size_t)(cq * 4 + 1) * Nq] = o1;
    O[(size_t)(cq * 4 + 2) * Nq] = o2;
    O[(size_t)(cq * 4 + 3) * Nq] = o3;
  }
}

// ---------------- launch ----------------
extern "C" void kernel_launch(void* const* d_in, const int* in_sizes, int n_in,
                              void* d_out, int out_size, void* d_ws, size_t ws_size,
                              hipStream_t stream) {
  const float* pts = (const float*)d_in[0];    // [B,N,3]
  const float* feats = (const float*)d_in[1];  // [B,C,N]
  float* out = (float*)d_out;                  // [B,C,N]

  char* ws = (char*)d_ws;
  size_t off = 0;
  auto alloc = [&](size_t bytes) {
    void* p = ws + off;
    off += (bytes + 255) & ~(size_t)255;
    return p;
  };
  float* sump = (float*)alloc((size_t)Bq * Nq * 4);
  int* fps_idx = (int*)alloc((size_t)Bq * NPq * 4);
  float* xyzq = (float*)alloc((size_t)Bq * NPq * 3 * 4);
  float* sumq = (float*)alloc((size_t)Bq * NPq * 4);
  float* coarse_t = (float*)alloc((size_t)Bq * NPq * Cq * 4);
  int* i0 = (int*)alloc((size_t)Bq * Nq * 4);
  int* i1 = (int*)alloc((size_t)Bq * Nq * 4);
  int* i2 = (int*)alloc((size_t)Bq * Nq * 4);
  float* w0 = (float*)alloc((size_t)Bq * Nq * 4);
  float* w1 = (float*)alloc((size_t)Bq * Nq * 4);
  float* w2 = (float*)alloc((size_t)Bq * Nq * 4);
  float* xqs = (float*)alloc((size_t)Bq * NPq * 4);
  float* yqs = (float*)alloc((size_t)Bq * NPq * 4);
  float* zqs = (float*)alloc((size_t)Bq * NPq * 4);

  k_sump<<<(Bq * Nq) / 256, 256, 0, stream>>>(pts, sump);
  k_fps<<<Bq, 512, 0, stream>>>(pts, fps_idx);
  k_gatherq<<<(Bq * NPq) / 256, 256, 0, stream>>>(pts, sump, fps_idx, xyzq, sumq, xqs, yqs, zqs);
  k_knn_group<<<Bq * NPq, 256, 0, stream>>>(pts, sump, xyzq, sumq, feats, coarse_t);
  k_three<<<(Bq * Nq) / 4, 256, 0, stream>>>(pts, sump, xqs, yqs, zqs, sumq, i0, i1, i2, w0, w1, w2);
  k_interp<<<(Bq * Nq) / 256, 256, 0, stream>>>(coarse_t, i0, i1, i2, w0, w1, w2, out);
}